// Round 6
// baseline (173.440 us; speedup 1.0000x reference)
//
#include <hip/hip_runtime.h>

#define N_NODES 50000
#define N_EDGES 640000
#define D 128          // D_IN == D_OUT
#define NB 8           // num bases
#define PAD 32         // bucket slots per dst (mean deg 12.8; overflow -> side list)
#define NSTRIP 3125    // 50000 / 16 row-strips

// Role split: bucket is the latency chain (atomicAdd -> dependent store per edge).
// 1024 bucket blocks -> 2.4 edges/thread (chain depth ~3 vs ~10 at 256 blocks).
// GEMM role was shown NOT to be the long pole (768 vs 1536 blocks: no change).
#define BUCKET_B 1024
#define GEMM_B   1024

typedef _Float16 half_t;
typedef __attribute__((ext_vector_type(8))) _Float16 half8;
typedef __attribute__((ext_vector_type(4))) float f32x4;

// ---- k0: zero counters + build Wt/Rt (fp16, transposed [n][k]) + zero y pad row ----
__global__ __launch_bounds__(256)
void init_kernel(const float* __restrict__ bases,
                 const float* __restrict__ comp,
                 const float* __restrict__ root,
                 half_t* __restrict__ Wt,
                 half_t* __restrict__ Rt,
                 half_t* __restrict__ y,
                 int* __restrict__ cnt,
                 int* __restrict__ novf) {
    int i = blockIdx.x * 256 + threadIdx.x;
    if (i == 0) *novf = 0;
    if (i < N_NODES) cnt[i] = 0;
    if (i < D) y[(size_t)N_NODES * D + i] = (half_t)0.f;   // zero row for gather padding
    if (i < D * D) {
        int ii = i >> 7, o = i & 127;
        float acc = 0.f;
#pragma unroll
        for (int b = 0; b < NB; ++b)
            acc += comp[b] * bases[((size_t)b * D + ii) * D + o];
        Wt[o * D + ii] = (half_t)acc;
        Rt[o * D + ii] = (half_t)root[i];
    }
}

// ---- k1 (fused): bucket role || gemm role (round-3 gemm body, direct stores) ----
__global__ __launch_bounds__(256, 4)
void fused_kernel(const float* __restrict__ x,
                  const half_t* __restrict__ Wt,   // [n][k]
                  const half_t* __restrict__ Rt,   // [n][k]
                  const float* __restrict__ bias,
                  const int* __restrict__ eidx,
                  half_t* __restrict__ y,
                  float* __restrict__ out,
                  int* __restrict__ cnt,
                  int* __restrict__ bucket,
                  int* __restrict__ ovf,
                  int* __restrict__ novf) {
    const int tid = threadIdx.x;

    if (blockIdx.x < BUCKET_B) {
        // ---------------- bucket role ----------------
        int t = blockIdx.x * 256 + tid;
        for (int e = t; e < N_EDGES; e += BUCKET_B * 256) {
            int src = eidx[e];
            int dst = eidx[N_EDGES + e];
            int pos = atomicAdd(&cnt[dst], 1);
            if (pos < PAD) {
                bucket[(size_t)dst * PAD + pos] = src;
            } else {            // P ~ 1e-7; capacity == E, never drops
                int k = atomicAdd(novf, 1);
                ovf[2 * k]     = src;
                ovf[2 * k + 1] = dst;
            }
        }
        return;
    }

    // ---------------- gemm role ----------------
    const int gb   = blockIdx.x - BUCKET_B;  // 0 .. GEMM_B-1
    const int wave = tid >> 6;
    const int lane = tid & 63;
    const int m    = lane & 15;
    const int quad = lane >> 4;
    const int q    = wave;                   // col quarter: nt = 2q, 2q+1
    const int s0   = gb;                     // starting M-strip
    const int SSTR = GEMM_B;

    // B fragments, loaded ONCE: B[k][n], n = lane&15, k = quad*8 + j
    half8 bw[2][4], br[2][4];
    float bb[2];
#pragma unroll
    for (int t = 0; t < 2; ++t) {
        const int nt = 2 * q + t;
        const half_t* wp = Wt + (nt * 16 + m) * D + quad * 8;
        const half_t* rp = Rt + (nt * 16 + m) * D + quad * 8;
#pragma unroll
        for (int kk = 0; kk < 4; ++kk) {
            bw[t][kk] = *(const half8*)(wp + kk * 32);
            br[t][kk] = *(const half8*)(rp + kk * 32);
        }
        bb[t] = bias[nt * 16 + m];
    }

    const float4* x4 = (const float4*)x;
    for (int s = s0; s < NSTRIP; s += SSTR) {
        // A fragment: A[m][k], row = s*16 + m, k = quad*8 + j
        size_t ab = (size_t)(s * 16 + m) * 32 + quad * 2;
        half8 a[4];
#pragma unroll
        for (int kk = 0; kk < 4; ++kk) {
            float4 v0 = x4[ab + kk * 8];
            float4 v1 = x4[ab + kk * 8 + 1];
            half8 h;
            h[0] = (half_t)v0.x; h[1] = (half_t)v0.y; h[2] = (half_t)v0.z; h[3] = (half_t)v0.w;
            h[4] = (half_t)v1.x; h[5] = (half_t)v1.y; h[6] = (half_t)v1.z; h[7] = (half_t)v1.w;
            a[kk] = h;
        }

        f32x4 accW[2], accR[2];
#pragma unroll
        for (int t = 0; t < 2; ++t) {
            accW[t] = (f32x4){0.f, 0.f, 0.f, 0.f};
            accR[t] = (f32x4){0.f, 0.f, 0.f, 0.f};
        }
#pragma unroll
        for (int t = 0; t < 2; ++t)
#pragma unroll
            for (int kk = 0; kk < 4; ++kk) {
                accW[t] = __builtin_amdgcn_mfma_f32_16x16x32_f16(a[kk], bw[t][kk], accW[t], 0, 0, 0);
                accR[t] = __builtin_amdgcn_mfma_f32_16x16x32_f16(a[kk], br[t][kk], accR[t], 0, 0, 0);
            }

        // C/D layout: col = lane&15, row = quad*4 + reg
#pragma unroll
        for (int t = 0; t < 2; ++t) {
            int col = (2 * q + t) * 16 + m;
#pragma unroll
            for (int r = 0; r < 4; ++r) {
                int row = s * 16 + quad * 4 + r;
                y[(size_t)row * D + col]   = (half_t)accW[t][r];
                out[(size_t)row * D + col] = accR[t][r] + bb[t];
            }
        }
    }
}

// ---- k2: gather, ONE WAVE PER NODE ----
// lane = g*16 + q: group g owns edge-quarter (<= 8 edges since c <= PAD=32);
// q owns col block q*8. All loads for a node issue in one batch (indices padded
// to the zeroed row N_NODES). Partials combine via shfl_xor(16,32); group 0
// does the coalesced out RMW. Serial chain per node: ONE load round-trip.
__global__ __launch_bounds__(256)
void gather_kernel(const int* __restrict__ cnt,
                   const int* __restrict__ bucket,
                   const half_t* __restrict__ y,
                   const int* __restrict__ ovf,
                   const int* __restrict__ novf,
                   float* __restrict__ out) {
    const int wave = threadIdx.x >> 6;
    const int lane = threadIdx.x & 63;
    const int g    = lane >> 4;
    const int q    = lane & 15;
    const int node = blockIdx.x * 4 + wave;
    if (node >= N_NODES) return;

    int c_raw = cnt[node];
    int c = c_raw > PAD ? PAD : c_raw;
    const int* bp = bucket + (size_t)node * PAD;

    int base = (c * g) >> 2;
    int ng   = ((c * (g + 1)) >> 2) - base;   // 0..8

    int idx[8];
#pragma unroll
    for (int j = 0; j < 8; ++j)
        idx[j] = (j < ng) ? bp[base + j] : N_NODES;   // pad -> zero row

    half8 v[8];
#pragma unroll
    for (int j = 0; j < 8; ++j)
        v[j] = *(const half8*)(y + (size_t)idx[j] * D + q * 8);

    float acc[8];
#pragma unroll
    for (int t = 0; t < 8; ++t)
        acc[t] = (((float)v[0][t] + (float)v[1][t]) + ((float)v[2][t] + (float)v[3][t]))
               + (((float)v[4][t] + (float)v[5][t]) + ((float)v[6][t] + (float)v[7][t]));

    if (c_raw > PAD) {               // rare: side-list scan, strided by group
        int n = *novf;
        for (int k = g; k < n; k += 4) {
            if (ovf[2 * k + 1] == node) {
                half8 w = *(const half8*)(y + (size_t)ovf[2 * k] * D + q * 8);
#pragma unroll
                for (int t = 0; t < 8; ++t) acc[t] += (float)w[t];
            }
        }
    }

#pragma unroll
    for (int t = 0; t < 8; ++t) {
        acc[t] += __shfl_xor(acc[t], 16);
        acc[t] += __shfl_xor(acc[t], 32);
    }

    if (g == 0) {
        float4* op = (float4*)(out + (size_t)node * D + q * 8);
        float4 o0 = op[0], o1 = op[1];
        o0.x += acc[0]; o0.y += acc[1]; o0.z += acc[2]; o0.w += acc[3];
        o1.x += acc[4]; o1.y += acc[5]; o1.z += acc[6]; o1.w += acc[7];
        op[0] = o0; op[1] = o1;
    }
}

extern "C" void kernel_launch(void* const* d_in, const int* in_sizes, int n_in,
                              void* d_out, int out_size, void* d_ws, size_t ws_size,
                              hipStream_t stream) {
    const float* x     = (const float*)d_in[0];
    const int*   eidx  = (const int*)d_in[1];
    const float* bases = (const float*)d_in[2];
    const float* comp  = (const float*)d_in[3];
    const float* root  = (const float*)d_in[4];
    const float* bias  = (const float*)d_in[5];
    float* out = (float*)d_out;

    char* ws = (char*)d_ws;
    half_t* y      = (half_t*)ws;                      // 12,800,512 B (50001 rows, padded)
    half_t* Wt     = (half_t*)(ws + 12800512);         //     32,768 B
    half_t* Rt     = (half_t*)(ws + 12833280);         //     32,768 B
    int*    cnt    = (int*)   (ws + 12866048);         //    200,000 B
    int*    bucket = (int*)   (ws + 13066048);         //  6,400,000 B
    int*    novf   = (int*)   (ws + 19466048);         //         16 B
    int*    ovf    = (int*)   (ws + 19466064);         //  5,120,000 B (capacity == E)

    init_kernel<<<(N_NODES + 255) / 256, 256, 0, stream>>>(
        bases, comp, root, Wt, Rt, y, cnt, novf);
    fused_kernel<<<BUCKET_B + GEMM_B, 256, 0, stream>>>(
        x, Wt, Rt, bias, eidx, y, out, cnt, bucket, ovf, novf);
    gather_kernel<<<(N_NODES + 3) / 4, 256, 0, stream>>>(
        cnt, bucket, y, ovf, novf, out);
}

// Round 7
// 163.552 us; speedup vs baseline: 1.0605x; 1.0605x over previous
//
#include <hip/hip_runtime.h>

#define N_NODES 50000
#define N_EDGES 640000
#define D 128          // D_IN == D_OUT
#define NB 8           // num bases
#define PAD 32         // bucket slots per dst (mean deg 12.8; overflow -> side list)
#define NSTRIP 3125    // 50000 / 16 row-strips

// Role split: 256 bucket blocks (proven optimum: contention-bound, more threads hurt)
// + 768 gemm blocks = 1024 blocks, 4/CU resident at __launch_bounds__(256,4).
// Bucket latency attacked via 4-wide batching (independent atomics in flight),
// NOT via more threads (round-6 regression: 1024 blocks -> +35% contention cost).
#define BUCKET_B 256
#define GEMM_B   768

typedef _Float16 half_t;
typedef __attribute__((ext_vector_type(8))) _Float16 half8;
typedef __attribute__((ext_vector_type(4))) float f32x4;

// ---- k0: zero counters + build Wt/Rt (fp16, transposed [n][k]) + zero y pad row ----
__global__ __launch_bounds__(256)
void init_kernel(const float* __restrict__ bases,
                 const float* __restrict__ comp,
                 const float* __restrict__ root,
                 half_t* __restrict__ Wt,
                 half_t* __restrict__ Rt,
                 half_t* __restrict__ y,
                 int* __restrict__ cnt,
                 int* __restrict__ novf) {
    int i = blockIdx.x * 256 + threadIdx.x;
    if (i == 0) *novf = 0;
    if (i < N_NODES) cnt[i] = 0;
    if (i < D) y[(size_t)N_NODES * D + i] = (half_t)0.f;   // zero row for gather padding
    if (i < D * D) {
        int ii = i >> 7, o = i & 127;
        float acc = 0.f;
#pragma unroll
        for (int b = 0; b < NB; ++b)
            acc += comp[b] * bases[((size_t)b * D + ii) * D + o];
        Wt[o * D + ii] = (half_t)acc;
        Rt[o * D + ii] = (half_t)root[i];
    }
}

// ---- k1 (fused): bucket role || gemm role ----
__global__ __launch_bounds__(256, 4)
void fused_kernel(const float* __restrict__ x,
                  const half_t* __restrict__ Wt,   // [n][k]
                  const half_t* __restrict__ Rt,   // [n][k]
                  const float* __restrict__ bias,
                  const int* __restrict__ eidx,
                  half_t* __restrict__ y,
                  float* __restrict__ out,
                  int* __restrict__ cnt,
                  int* __restrict__ bucket,
                  int* __restrict__ ovf,
                  int* __restrict__ novf) {
    const int tid = threadIdx.x;

    if (blockIdx.x < BUCKET_B) {
        // ---------------- bucket role: 4-wide batched ----------------
        // int4 loads of 4 consecutive edges; 4 INDEPENDENT atomicAdds issue
        // back-to-back (overlapped latency), then 4 stores. Chain depth per
        // thread: ~2.4 atomic round-trips instead of ~10.
        const int4* s4 = (const int4*)eidx;
        const int4* d4 = (const int4*)(eidx + N_EDGES);
        const int NG = N_EDGES / 4;                // 160000 groups, E%4==0
        for (int g = blockIdx.x * 256 + tid; g < NG; g += BUCKET_B * 256) {
            int4 sv = s4[g];
            int4 dv = d4[g];
            int p0 = atomicAdd(&cnt[dv.x], 1);
            int p1 = atomicAdd(&cnt[dv.y], 1);
            int p2 = atomicAdd(&cnt[dv.z], 1);
            int p3 = atomicAdd(&cnt[dv.w], 1);
            if (p0 < PAD) bucket[(size_t)dv.x * PAD + p0] = sv.x;
            else { int k = atomicAdd(novf, 1); ovf[2 * k] = sv.x; ovf[2 * k + 1] = dv.x; }
            if (p1 < PAD) bucket[(size_t)dv.y * PAD + p1] = sv.y;
            else { int k = atomicAdd(novf, 1); ovf[2 * k] = sv.y; ovf[2 * k + 1] = dv.y; }
            if (p2 < PAD) bucket[(size_t)dv.z * PAD + p2] = sv.z;
            else { int k = atomicAdd(novf, 1); ovf[2 * k] = sv.z; ovf[2 * k + 1] = dv.z; }
            if (p3 < PAD) bucket[(size_t)dv.w * PAD + p3] = sv.w;
            else { int k = atomicAdd(novf, 1); ovf[2 * k] = sv.w; ovf[2 * k + 1] = dv.w; }
        }
        return;
    }

    // ---------------- gemm role ----------------
    const int gb   = blockIdx.x - BUCKET_B;  // 0 .. GEMM_B-1
    const int wave = tid >> 6;
    const int lane = tid & 63;
    const int m    = lane & 15;
    const int quad = lane >> 4;
    const int q    = wave;                   // col quarter: nt = 2q, 2q+1
    const int s0   = gb;                     // starting M-strip
    const int SSTR = GEMM_B;

    // B fragments, loaded ONCE: B[k][n], n = lane&15, k = quad*8 + j
    half8 bw[2][4], br[2][4];
    float bb[2];
#pragma unroll
    for (int t = 0; t < 2; ++t) {
        const int nt = 2 * q + t;
        const half_t* wp = Wt + (nt * 16 + m) * D + quad * 8;
        const half_t* rp = Rt + (nt * 16 + m) * D + quad * 8;
#pragma unroll
        for (int kk = 0; kk < 4; ++kk) {
            bw[t][kk] = *(const half8*)(wp + kk * 32);
            br[t][kk] = *(const half8*)(rp + kk * 32);
        }
        bb[t] = bias[nt * 16 + m];
    }

    const float4* x4 = (const float4*)x;
    for (int s = s0; s < NSTRIP; s += SSTR) {
        // A fragment: A[m][k], row = s*16 + m, k = quad*8 + j
        size_t ab = (size_t)(s * 16 + m) * 32 + quad * 2;
        half8 a[4];
#pragma unroll
        for (int kk = 0; kk < 4; ++kk) {
            float4 v0 = x4[ab + kk * 8];
            float4 v1 = x4[ab + kk * 8 + 1];
            half8 h;
            h[0] = (half_t)v0.x; h[1] = (half_t)v0.y; h[2] = (half_t)v0.z; h[3] = (half_t)v0.w;
            h[4] = (half_t)v1.x; h[5] = (half_t)v1.y; h[6] = (half_t)v1.z; h[7] = (half_t)v1.w;
            a[kk] = h;
        }

        f32x4 accW[2], accR[2];
#pragma unroll
        for (int t = 0; t < 2; ++t) {
            accW[t] = (f32x4){0.f, 0.f, 0.f, 0.f};
            accR[t] = (f32x4){0.f, 0.f, 0.f, 0.f};
        }
#pragma unroll
        for (int t = 0; t < 2; ++t)
#pragma unroll
            for (int kk = 0; kk < 4; ++kk) {
                accW[t] = __builtin_amdgcn_mfma_f32_16x16x32_f16(a[kk], bw[t][kk], accW[t], 0, 0, 0);
                accR[t] = __builtin_amdgcn_mfma_f32_16x16x32_f16(a[kk], br[t][kk], accR[t], 0, 0, 0);
            }

        // C/D layout: col = lane&15, row = quad*4 + reg
#pragma unroll
        for (int t = 0; t < 2; ++t) {
            int col = (2 * q + t) * 16 + m;
#pragma unroll
            for (int r = 0; r < 4; ++r) {
                int row = s * 16 + quad * 4 + r;
                y[(size_t)row * D + col]   = (half_t)accW[t][r];
                out[(size_t)row * D + col] = accR[t][r] + bb[t];
            }
        }
    }
}

// ---- k2: gather, ONE WAVE PER NODE ----
// lane = g*16 + q: group g owns edge-quarter (<= 8 edges since c <= PAD=32);
// q owns col block q*8. All loads for a node issue in one batch (indices padded
// to the zeroed row N_NODES). Partials combine via shfl_xor(16,32); group 0
// does the coalesced out RMW. Serial chain per node: ONE load round-trip.
__global__ __launch_bounds__(256)
void gather_kernel(const int* __restrict__ cnt,
                   const int* __restrict__ bucket,
                   const half_t* __restrict__ y,
                   const int* __restrict__ ovf,
                   const int* __restrict__ novf,
                   float* __restrict__ out) {
    const int wave = threadIdx.x >> 6;
    const int lane = threadIdx.x & 63;
    const int g    = lane >> 4;
    const int q    = lane & 15;
    const int node = blockIdx.x * 4 + wave;
    if (node >= N_NODES) return;

    int c_raw = cnt[node];
    int c = c_raw > PAD ? PAD : c_raw;
    const int* bp = bucket + (size_t)node * PAD;

    int base = (c * g) >> 2;
    int ng   = ((c * (g + 1)) >> 2) - base;   // 0..8

    int idx[8];
#pragma unroll
    for (int j = 0; j < 8; ++j)
        idx[j] = (j < ng) ? bp[base + j] : N_NODES;   // pad -> zero row

    half8 v[8];
#pragma unroll
    for (int j = 0; j < 8; ++j)
        v[j] = *(const half8*)(y + (size_t)idx[j] * D + q * 8);

    float acc[8];
#pragma unroll
    for (int t = 0; t < 8; ++t)
        acc[t] = (((float)v[0][t] + (float)v[1][t]) + ((float)v[2][t] + (float)v[3][t]))
               + (((float)v[4][t] + (float)v[5][t]) + ((float)v[6][t] + (float)v[7][t]));

    if (c_raw > PAD) {               // rare: side-list scan, strided by group
        int n = *novf;
        for (int k = g; k < n; k += 4) {
            if (ovf[2 * k + 1] == node) {
                half8 w = *(const half8*)(y + (size_t)ovf[2 * k] * D + q * 8);
#pragma unroll
                for (int t = 0; t < 8; ++t) acc[t] += (float)w[t];
            }
        }
    }

#pragma unroll
    for (int t = 0; t < 8; ++t) {
        acc[t] += __shfl_xor(acc[t], 16);
        acc[t] += __shfl_xor(acc[t], 32);
    }

    if (g == 0) {
        float4* op = (float4*)(out + (size_t)node * D + q * 8);
        float4 o0 = op[0], o1 = op[1];
        o0.x += acc[0]; o0.y += acc[1]; o0.z += acc[2]; o0.w += acc[3];
        o1.x += acc[4]; o1.y += acc[5]; o1.z += acc[6]; o1.w += acc[7];
        op[0] = o0; op[1] = o1;
    }
}

extern "C" void kernel_launch(void* const* d_in, const int* in_sizes, int n_in,
                              void* d_out, int out_size, void* d_ws, size_t ws_size,
                              hipStream_t stream) {
    const float* x     = (const float*)d_in[0];
    const int*   eidx  = (const int*)d_in[1];
    const float* bases = (const float*)d_in[2];
    const float* comp  = (const float*)d_in[3];
    const float* root  = (const float*)d_in[4];
    const float* bias  = (const float*)d_in[5];
    float* out = (float*)d_out;

    char* ws = (char*)d_ws;
    half_t* y      = (half_t*)ws;                      // 12,800,512 B (50001 rows, padded)
    half_t* Wt     = (half_t*)(ws + 12800512);         //     32,768 B
    half_t* Rt     = (half_t*)(ws + 12833280);         //     32,768 B
    int*    cnt    = (int*)   (ws + 12866048);         //    200,000 B
    int*    bucket = (int*)   (ws + 13066048);         //  6,400,000 B
    int*    novf   = (int*)   (ws + 19466048);         //         16 B
    int*    ovf    = (int*)   (ws + 19466064);         //  5,120,000 B (capacity == E)

    init_kernel<<<(N_NODES + 255) / 256, 256, 0, stream>>>(
        bases, comp, root, Wt, Rt, y, cnt, novf);
    fused_kernel<<<BUCKET_B + GEMM_B, 256, 0, stream>>>(
        x, Wt, Rt, bias, eidx, y, out, cnt, bucket, ovf, novf);
    gather_kernel<<<(N_NODES + 3) / 4, 256, 0, stream>>>(
        cnt, bucket, y, ovf, novf, out);
}